// Round 19
// baseline (26.225 us; speedup 1.0000x reference)
//
#include <hip/hip_runtime.h>

#define NB 4
#define NV 4096
#define NF 8192
#define NP 6
#define NE 2048

#define NBLK 768          // 3 blocks/CU x 256 CU -> one execution round
#define BPB  (NBLK / NB)  // 192 vol slices per batch
#define CTR  (2 * NBLK)   // counter base in ws (floats): L1 g at CTR+g*16, L2 at CTR+192

typedef short bf16x8  __attribute__((ext_vector_type(8)));
typedef float f32x16  __attribute__((ext_vector_type(16)));

// round-to-nearest-even fp32 -> bf16 (as ushort)
__device__ __forceinline__ unsigned short bf16_rn(float x) {
    unsigned int u = __float_as_uint(x);
    u = (u + 0x7FFFu + ((u >> 16) & 1u)) >> 16;
    return (unsigned short)u;
}
__device__ __forceinline__ float bf16f(unsigned short h) {
    return __uint_as_float(((unsigned int)h) << 16);
}

// agent-scope atomics. Publish is relaxed (ordering provided by the
// release RMW that follows); reads on the finalizer side are ACQUIRE.
__device__ __forceinline__ void pub_f(float* p, float v) {
    __hip_atomic_store((unsigned int*)p, __float_as_uint(v),
                       __ATOMIC_RELAXED, __HIP_MEMORY_SCOPE_AGENT);
}
__device__ __forceinline__ float rd_acq_f(const float* p) {
    unsigned int u = __hip_atomic_load((const unsigned int*)p,
                                       __ATOMIC_ACQUIRE, __HIP_MEMORY_SCOPE_AGENT);
    return __uint_as_float(u);
}
__device__ __forceinline__ unsigned int ctr_add_acqrel(float* p) {
    return __hip_atomic_fetch_add((unsigned int*)p, 1u,
                                  __ATOMIC_ACQ_REL, __HIP_MEMORY_SCOPE_AGENT);
}

// ---------------------------------------------------------------------------
// Single kernel: R14 MFMA body + sharded last-block finalize with a proper
// acquire/release chain (R18 post-mortem: relaxed RMWs gave no happens-before,
// finalizer read uninitialized partials on the first call).
//   publisher: partial stores -> ACQ_REL RMW on L1 counter (release publishes)
//   group-last (o1&63==63): its acquire syncs the group's 64 publishes,
//                           then ACQ_REL RMW on L2 counter (release, transitive)
//   12th L2 RMW (o2%12==11): acquire syncs ALL publishes -> finalize with
//                            ACQUIRE loads.
// Each launch adds exactly 64 per L1 and 12 to L2 -> residue selection correct
// for any starting value (poison-safe, replay-safe, deterministic).
// ---------------------------------------------------------------------------
__global__ __launch_bounds__(256, 3) void fused_kernel(
    const float* __restrict__ xs,
    const float* __restrict__ pm,
    const float* __restrict__ em,
    const int*   __restrict__ faces,
    const float* __restrict__ tv,
    float* __restrict__ ws,
    float* __restrict__ out)
{
    __shared__ unsigned short Apack[NE][8];   // 32 KB
    __shared__ unsigned short Bpack[128][8];  // 2 KB
    __shared__ float x2s[128];
    __shared__ float pmin[4][128];
    __shared__ float redv[256];
    __shared__ float ch[128];
    __shared__ unsigned int sFin;

    const int bid  = blockIdx.x;
    const int tid  = threadIdx.x;
    const int lane = tid & 63;
    const int w    = tid >> 6;

    // ---------------- volume slice ------------------------------------------
    {
        const int vb   = bid / BPB;
        const int j    = bid % BPB;
        const int fs   = (j * NF) / BPB;
        const int fcnt = (((j + 1) * NF) / BPB) - fs;   // 42 or 43
        float fvol = 0.0f;
        if (tid < fcnt) {
            const int* fp = faces + (size_t)(vb * NF + fs + tid) * 3;
            int i0 = fp[0], i1 = fp[1], i2 = fp[2];
            const float* p0 = xs + (size_t)(vb * NV + i0) * 3;
            const float* p1 = xs + (size_t)(vb * NV + i1) * 3;
            const float* p2 = xs + (size_t)(vb * NV + i2) * 3;
            float a0 = p0[0], a1 = p0[1], a2 = p0[2];
            float b0 = p1[0], b1 = p1[1], b2 = p1[2];
            float c0 = p2[0], c1 = p2[1], c2 = p2[2];
            float crx = a1 * b2 - a2 * b1;
            float cry = a2 * b0 - a0 * b2;
            float crz = a0 * b1 - a1 * b0;
            fvol = (crx * c0 + cry * c1 + crz * c2) * (1.0f / 6.0f);
        }
        redv[tid] = fvol;
    }

    const int chunk = bid & 31;
    const int pp    = bid >> 5;            // b*NP + p
    const int p     = pp % NP;
    const int b     = pp / NP;

    // ---------------- stage edges: 8 per thread, packed bf16 hi/lo ----------
    {
        const float2* e2 = (const float2*)em + (size_t)pp * NE;
#pragma unroll
        for (int i = 0; i < 8; ++i) {
            int ee = i * 256 + tid;
            float2 e = e2[ee];
            float ax = -2.0f * e.x, ay = -2.0f * e.y;
            float cc = fmaf(e.x, e.x, e.y * e.y);
            unsigned int axh = bf16_rn(ax);
            unsigned int axl = bf16_rn(ax - bf16f((unsigned short)axh));
            unsigned int ayh = bf16_rn(ay);
            unsigned int ayl = bf16_rn(ay - bf16f((unsigned short)ayh));
            unsigned int cch = bf16_rn(cc);
            unsigned int ccl = bf16_rn(cc - bf16f((unsigned short)cch));
            uint4 pk;
            pk.x = axh | (axh << 16);      // k0,k1
            pk.y = axl | (ayh << 16);      // k2,k3
            pk.z = ayh | (ayl << 16);      // k4,k5
            pk.w = cch | (ccl << 16);      // k6,k7
            *(uint4*)&Apack[ee][0] = pk;
        }
    }

    // ---------------- stage points: project + pack --------------------------
    if (tid < 128) {
        int v = chunk * 128 + tid;
        const float* x3 = xs + (size_t)(b * NV + v) * 3;
        float x = x3[0], y = x3[1], z = x3[2];
        const float* M = pm + p * 12;                  // uniform -> s_load
        float px = fmaf(M[0], x, fmaf(M[1], y, fmaf(M[2],  z, M[3])));
        float py = fmaf(M[4], x, fmaf(M[5], y, fmaf(M[6],  z, M[7])));
        float pz = fmaf(M[8], x, fmaf(M[9], y, fmaf(M[10], z, M[11])));
        float inv = 1.0f / pz;
        float X = px * inv, Y = py * inv;
        x2s[tid] = fmaf(X, X, Y * Y);
        unsigned int xh = bf16_rn(X);
        unsigned int xl = bf16_rn(X - bf16f((unsigned short)xh));
        unsigned int yh = bf16_rn(Y);
        unsigned int yl = bf16_rn(Y - bf16f((unsigned short)yh));
        uint4 pk;
        pk.x = xh | (xl << 16);            // k0,k1
        pk.y = xh | (yh << 16);            // k2,k3
        pk.z = yl | (yh << 16);            // k4,k5
        pk.w = 0x3F80u | (0x3F80u << 16);  // k6,k7 = 1.0, 1.0
        *(uint4*)&Bpack[tid][0] = pk;
    }
    __syncthreads();

    // ---------------- MFMA main loop ----------------------------------------
    const bf16x8 zfrag = {0, 0, 0, 0, 0, 0, 0, 0};
    const f32x16 zacc  = {0.f, 0.f, 0.f, 0.f, 0.f, 0.f, 0.f, 0.f,
                          0.f, 0.f, 0.f, 0.f, 0.f, 0.f, 0.f, 0.f};

    bf16x8 bfrag[4];
#pragma unroll
    for (int t = 0; t < 4; ++t)
        bfrag[t] = (lane < 32) ? *(const bf16x8*)&Bpack[t * 32 + lane][0] : zfrag;

    float rm[4] = {3.4e38f, 3.4e38f, 3.4e38f, 3.4e38f};

#pragma unroll 2
    for (int et = 0; et < 16; ++et) {
        bf16x8 afrag = (lane < 32)
                         ? *(const bf16x8*)&Apack[(w * 16 + et) * 32 + lane][0]
                         : zfrag;
#pragma unroll
        for (int t = 0; t < 4; ++t) {
            f32x16 c = __builtin_amdgcn_mfma_f32_32x32x16_bf16(afrag, bfrag[t], zacc, 0, 0, 0);
            float m = fminf(c[0], c[1]);
            m = fminf(fminf(m, c[2]),  c[3]);    // v_min3 chain
            m = fminf(fminf(m, c[4]),  c[5]);
            m = fminf(fminf(m, c[6]),  c[7]);
            m = fminf(fminf(m, c[8]),  c[9]);
            m = fminf(fminf(m, c[10]), c[11]);
            m = fminf(fminf(m, c[12]), c[13]);
            m = fminf(fminf(m, c[14]), c[15]);
            rm[t] = fminf(rm[t], m);
        }
    }

#pragma unroll
    for (int t = 0; t < 4; ++t)
        rm[t] = fminf(rm[t], __shfl_xor(rm[t], 32));
    if (lane < 32) {
#pragma unroll
        for (int t = 0; t < 4; ++t)
            pmin[w][t * 32 + lane] = rm[t];
    }
    __syncthreads();

    // ---------------- combine waves, add x^2, reduce -------------------------
    if (tid < 128) {
        ch[tid] = fminf(fminf(pmin[0][tid], pmin[1][tid]),
                        fminf(pmin[2][tid], pmin[3][tid])) + x2s[tid];
    }
    __syncthreads();

    if (tid < 128) redv[tid] += redv[tid + 128];
    __syncthreads();
    for (int st = 64; st > 0; st >>= 1) {
        if (tid < st) {
            redv[tid] += redv[tid + st];
            ch[tid]   += ch[tid + st];
        }
        __syncthreads();
    }

    // ---------------- publish partials + acq/rel sharded counters ------------
    if (tid == 0) {
        pub_f(&ws[bid],        ch[0]);
        pub_f(&ws[NBLK + bid], redv[0]);
        asm volatile("s_waitcnt vmcnt(0)" ::: "memory");   // stores done first
        unsigned int fin = 0u;
        unsigned int g = (unsigned int)bid >> 6;           // 12 groups of 64
        unsigned int o1 = ctr_add_acqrel(ws + CTR + g * 16);   // release publish
        if ((o1 & 63u) == 63u) {                           // group complete
            unsigned int o2 = ctr_add_acqrel(ws + CTR + 192);  // transitive rel
            fin = (o2 % 12u == 11u) ? 1u : 0u;             // all groups done
        }
        sFin = fin;
    }
    __syncthreads();

    // ---------------- finalizer block writes out[8] --------------------------
    if (sFin) {
        const int fb = tid >> 6;                       // wave -> batch
        const int fl = tid & 63;
        const float* cp = ws + fb * BPB + fl * 3;      // 192 chamfer partials
        const float* vp = ws + NBLK + fb * BPB + fl * 3;
        float cs = rd_acq_f(cp + 0) + rd_acq_f(cp + 1) + rd_acq_f(cp + 2);
        float vs = rd_acq_f(vp + 0) + rd_acq_f(vp + 1) + rd_acq_f(vp + 2);
#pragma unroll
        for (int off = 1; off < 64; off <<= 1) {
            cs += __shfl_xor(cs, off);
            vs += __shfl_xor(vs, off);
        }
        if (fl == 0) {
            out[fb] = cs * (1.0f / (NP * NV));
            float d = fabsf(vs) - tv[fb];
            out[4 + fb] = d * d;
        }
    }
}

// ---------------------------------------------------------------------------
extern "C" void kernel_launch(void* const* d_in, const int* in_sizes, int n_in,
                              void* d_out, int out_size, void* d_ws, size_t ws_size,
                              hipStream_t stream) {
    const float* xs    = (const float*)d_in[0];
    const float* pm    = (const float*)d_in[1];
    const float* em    = (const float*)d_in[2];
    const int*   faces = (const int*)d_in[3];
    const float* tv    = (const float*)d_in[4];
    float* out = (float*)d_out;
    float* ws  = (float*)d_ws;   // partials [0,1536); counters at [1536,1736)

    fused_kernel<<<NBLK, 256, 0, stream>>>(xs, pm, em, faces, tv, ws, out);
}

// Round 20
// 15.948 us; speedup vs baseline: 1.6444x; 1.6444x over previous
//
#include <hip/hip_runtime.h>

#define NB 4
#define NV 4096
#define NF 8192
#define NP 6
#define NE 2048

#define NBLK 768          // 3 blocks/CU x 256 CU -> one execution round
#define BPB  (NBLK / NB)  // 192 vol slices per batch

typedef short bf16x8  __attribute__((ext_vector_type(8)));
typedef float f32x16  __attribute__((ext_vector_type(16)));

// round-to-nearest-even fp32 -> bf16 (as ushort)
__device__ __forceinline__ unsigned short bf16_rn(float x) {
    unsigned int u = __float_as_uint(x);
    u = (u + 0x7FFFu + ((u >> 16) & 1u)) >> 16;
    return (unsigned short)u;
}
__device__ __forceinline__ float bf16f(unsigned short h) {
    return __uint_as_float(((unsigned int)h) << 16);
}

// ---------------------------------------------------------------------------
// Fused kernel (R14 champion body; epilogue = 1-barrier wave-shuffle reduce).
// Per block: volume slice -> ws[NBLK+bid]; chamfer chunk (128 points x 2048
// edges) -> ws[bid]. Chamfer via mfma_f32_32x32x16_bf16 with bf16 hi/lo
// split-precision (exact to ~2^-18 rel):
//   A[e] = {axh,axh,axl, ayh,ayh,ayl, cch,ccl}, B[v] = {xh,xl,xh, yh,yl,yh, 1,1}
// x^2 added after the min (min(c)+s == min(c+s) exactly).
// ---------------------------------------------------------------------------
__global__ __launch_bounds__(256, 3) void fused_kernel(
    const float* __restrict__ xs,
    const float* __restrict__ pm,
    const float* __restrict__ em,
    const int*   __restrict__ faces,
    float* __restrict__ ws)
{
    __shared__ unsigned short Apack[NE][8];   // 32 KB
    __shared__ unsigned short Bpack[128][8];  // 2 KB
    __shared__ float x2s[128];
    __shared__ float pmin[4][128];
    __shared__ float redv[256];
    __shared__ float ch[128];

    const int bid  = blockIdx.x;
    const int tid  = threadIdx.x;
    const int lane = tid & 63;
    const int w    = tid >> 6;

    // ---------------- volume slice ------------------------------------------
    {
        const int vb   = bid / BPB;
        const int j    = bid % BPB;
        const int fs   = (j * NF) / BPB;
        const int fcnt = (((j + 1) * NF) / BPB) - fs;   // 42 or 43
        float fvol = 0.0f;
        if (tid < fcnt) {
            const int* fp = faces + (size_t)(vb * NF + fs + tid) * 3;
            int i0 = fp[0], i1 = fp[1], i2 = fp[2];
            const float* p0 = xs + (size_t)(vb * NV + i0) * 3;
            const float* p1 = xs + (size_t)(vb * NV + i1) * 3;
            const float* p2 = xs + (size_t)(vb * NV + i2) * 3;
            float a0 = p0[0], a1 = p0[1], a2 = p0[2];
            float b0 = p1[0], b1 = p1[1], b2 = p1[2];
            float c0 = p2[0], c1 = p2[1], c2 = p2[2];
            float crx = a1 * b2 - a2 * b1;
            float cry = a2 * b0 - a0 * b2;
            float crz = a0 * b1 - a1 * b0;
            fvol = (crx * c0 + cry * c1 + crz * c2) * (1.0f / 6.0f);
        }
        redv[tid] = fvol;
    }

    const int chunk = bid & 31;
    const int pp    = bid >> 5;            // b*NP + p
    const int p     = pp % NP;
    const int b     = pp / NP;

    // ---------------- stage edges: 8 per thread, packed bf16 hi/lo ----------
    {
        const float2* e2 = (const float2*)em + (size_t)pp * NE;
#pragma unroll
        for (int i = 0; i < 8; ++i) {
            int ee = i * 256 + tid;
            float2 e = e2[ee];
            float ax = -2.0f * e.x, ay = -2.0f * e.y;
            float cc = fmaf(e.x, e.x, e.y * e.y);
            unsigned int axh = bf16_rn(ax);
            unsigned int axl = bf16_rn(ax - bf16f((unsigned short)axh));
            unsigned int ayh = bf16_rn(ay);
            unsigned int ayl = bf16_rn(ay - bf16f((unsigned short)ayh));
            unsigned int cch = bf16_rn(cc);
            unsigned int ccl = bf16_rn(cc - bf16f((unsigned short)cch));
            uint4 pk;
            pk.x = axh | (axh << 16);      // k0,k1
            pk.y = axl | (ayh << 16);      // k2,k3
            pk.z = ayh | (ayl << 16);      // k4,k5
            pk.w = cch | (ccl << 16);      // k6,k7
            *(uint4*)&Apack[ee][0] = pk;
        }
    }

    // ---------------- stage points: project + pack --------------------------
    if (tid < 128) {
        int v = chunk * 128 + tid;
        const float* x3 = xs + (size_t)(b * NV + v) * 3;
        float x = x3[0], y = x3[1], z = x3[2];
        const float* M = pm + p * 12;                  // uniform -> s_load
        float px = fmaf(M[0], x, fmaf(M[1], y, fmaf(M[2],  z, M[3])));
        float py = fmaf(M[4], x, fmaf(M[5], y, fmaf(M[6],  z, M[7])));
        float pz = fmaf(M[8], x, fmaf(M[9], y, fmaf(M[10], z, M[11])));
        float inv = 1.0f / pz;
        float X = px * inv, Y = py * inv;
        x2s[tid] = fmaf(X, X, Y * Y);
        unsigned int xh = bf16_rn(X);
        unsigned int xl = bf16_rn(X - bf16f((unsigned short)xh));
        unsigned int yh = bf16_rn(Y);
        unsigned int yl = bf16_rn(Y - bf16f((unsigned short)yh));
        uint4 pk;
        pk.x = xh | (xl << 16);            // k0,k1
        pk.y = xh | (yh << 16);            // k2,k3
        pk.z = yl | (yh << 16);            // k4,k5
        pk.w = 0x3F80u | (0x3F80u << 16);  // k6,k7 = 1.0, 1.0
        *(uint4*)&Bpack[tid][0] = pk;
    }
    __syncthreads();

    // ---------------- MFMA main loop ----------------------------------------
    const bf16x8 zfrag = {0, 0, 0, 0, 0, 0, 0, 0};
    const f32x16 zacc  = {0.f, 0.f, 0.f, 0.f, 0.f, 0.f, 0.f, 0.f,
                          0.f, 0.f, 0.f, 0.f, 0.f, 0.f, 0.f, 0.f};

    bf16x8 bfrag[4];
#pragma unroll
    for (int t = 0; t < 4; ++t)
        bfrag[t] = (lane < 32) ? *(const bf16x8*)&Bpack[t * 32 + lane][0] : zfrag;

    float rm[4] = {3.4e38f, 3.4e38f, 3.4e38f, 3.4e38f};

#pragma unroll 2
    for (int et = 0; et < 16; ++et) {
        bf16x8 afrag = (lane < 32)
                         ? *(const bf16x8*)&Apack[(w * 16 + et) * 32 + lane][0]
                         : zfrag;
#pragma unroll
        for (int t = 0; t < 4; ++t) {
            f32x16 c = __builtin_amdgcn_mfma_f32_32x32x16_bf16(afrag, bfrag[t], zacc, 0, 0, 0);
            float m = fminf(c[0], c[1]);
            m = fminf(fminf(m, c[2]),  c[3]);    // v_min3 chain
            m = fminf(fminf(m, c[4]),  c[5]);
            m = fminf(fminf(m, c[6]),  c[7]);
            m = fminf(fminf(m, c[8]),  c[9]);
            m = fminf(fminf(m, c[10]), c[11]);
            m = fminf(fminf(m, c[12]), c[13]);
            m = fminf(fminf(m, c[14]), c[15]);
            rm[t] = fminf(rm[t], m);
        }
    }

#pragma unroll
    for (int t = 0; t < 4; ++t)
        rm[t] = fminf(rm[t], __shfl_xor(rm[t], 32));
    if (lane < 32) {
#pragma unroll
        for (int t = 0; t < 4; ++t)
            pmin[w][t * 32 + lane] = rm[t];
    }
    __syncthreads();

    // ---------------- combine waves, add x^2 --------------------------------
    if (tid < 128) {
        ch[tid] = fminf(fminf(pmin[0][tid], pmin[1][tid]),
                        fminf(pmin[2][tid], pmin[3][tid])) + x2s[tid];
    }
    __syncthreads();

    // ---------------- single-wave shuffle epilogue (1 barrier total) --------
    if (w == 0) {
        float cs = ch[lane] + ch[lane + 64];
        float vs = (redv[lane] + redv[lane + 64]) +
                   (redv[lane + 128] + redv[lane + 192]);
#pragma unroll
        for (int off = 1; off < 64; off <<= 1) {
            cs += __shfl_xor(cs, off);
            vs += __shfl_xor(vs, off);
        }
        if (lane == 0) {
            ws[bid]        = cs;
            ws[NBLK + bid] = vs;
        }
    }
}

// ---------------------------------------------------------------------------
// Finalize: 1 block, 256 threads; wave b handles batch b. Deterministic.
// ---------------------------------------------------------------------------
__global__ __launch_bounds__(256) void finalize_kernel(
    const float* __restrict__ ws,
    const float* __restrict__ tv,
    float* __restrict__ out)
{
    const int tid  = threadIdx.x;
    const int b    = tid >> 6;
    const int lane = tid & 63;

    const float* cp = ws + b * BPB + lane * 3;            // 192 chamfer partials
    const float* vp = ws + NBLK + b * BPB + lane * 3;     // 192 vol partials
    float cs = cp[0] + cp[1] + cp[2];
    float vs = vp[0] + vp[1] + vp[2];
#pragma unroll
    for (int off = 1; off < 64; off <<= 1) {
        cs += __shfl_xor(cs, off);
        vs += __shfl_xor(vs, off);
    }
    if (lane == 0) {
        out[b] = cs * (1.0f / (NP * NV));
        float d = fabsf(vs) - tv[b];
        out[4 + b] = d * d;
    }
}

// ---------------------------------------------------------------------------
extern "C" void kernel_launch(void* const* d_in, const int* in_sizes, int n_in,
                              void* d_out, int out_size, void* d_ws, size_t ws_size,
                              hipStream_t stream) {
    const float* xs    = (const float*)d_in[0];
    const float* pm    = (const float*)d_in[1];
    const float* em    = (const float*)d_in[2];
    const int*   faces = (const int*)d_in[3];
    const float* tv    = (const float*)d_in[4];
    float* out = (float*)d_out;
    float* ws  = (float*)d_ws;            // 1536 floats of partials

    fused_kernel<<<NBLK, 256, 0, stream>>>(xs, pm, em, faces, ws);
    finalize_kernel<<<1, 256, 0, stream>>>(ws, tv, out);
}